// Round 5
// baseline (12178.312 us; speedup 1.0000x reference)
//
#include <hip/hip_runtime.h>
#include <stdint.h>

#define SEQ   512
#define NB    256      // batch
#define SW    2048     // stream width
#define STW   1792     // state width
#define INW   256      // input width
#define NBLK  256
#define NTHR  256

typedef float f32x4 __attribute__((ext_vector_type(4)));

// workspace layout (bytes)
// [0,4096): 4 group flag arrays, 1024B apart: flags[cb] per block
// [4096]: global abort flag
#define WS_S32A  8192
#define WS_S32B  (WS_S32A + NB*SW*4)
#define WS_S8A   (WS_S32B + NB*SW*4)
#define WS_S8B   (WS_S8A + NB*SW)
#define WS_H8    (WS_S8B + NB*SW)

// S8'/H8' chunk-major layout: [(bb*4+strip)*64 + chunk]*512 + l*8
// where element (l, j) = row (strip*16 + (l&15)), k = chunk*32 + (l>>4)*8 + j
#define CHUNK_OFF(bb,strip,ch) (((size_t)(((bb)*4+(strip))*64 + (ch)))*512)

// ---------- agent-scope (sc1) access helpers: stores write through to the
// coherence point; loads used ONLY for sync flags (must never cache) ----------
__device__ __forceinline__ unsigned ald32(const void* p){
  return __hip_atomic_load((const unsigned*)p, __ATOMIC_RELAXED, __HIP_MEMORY_SCOPE_AGENT);
}
__device__ __forceinline__ void ast64(void* p, uint64_t v){
  __hip_atomic_store((uint64_t*)p, v, __ATOMIC_RELAXED, __HIP_MEMORY_SCOPE_AGENT);
}
__device__ __forceinline__ void ast32(void* p, unsigned v){
  __hip_atomic_store((unsigned*)p, v, __ATOMIC_RELAXED, __HIP_MEMORY_SCOPE_AGENT);
}

__device__ __forceinline__ uint8_t f2fp8(float v){
  int p = __builtin_amdgcn_cvt_pk_fp8_f32(v, 0.0f, 0, false);
  return (uint8_t)(p & 0xFF);
}

__device__ __forceinline__ void store_fp8x8(uint8_t* dst, float4 a, float4 b){
  int lo = 0, hi = 0;
  lo = __builtin_amdgcn_cvt_pk_fp8_f32(a.x, a.y, lo, false);
  lo = __builtin_amdgcn_cvt_pk_fp8_f32(a.z, a.w, lo, true);
  hi = __builtin_amdgcn_cvt_pk_fp8_f32(b.x, b.y, hi, false);
  hi = __builtin_amdgcn_cvt_pk_fp8_f32(b.z, b.w, hi, true);
  int2 v; v.x = lo; v.y = hi;
  *reinterpret_cast<int2*>(dst) = v;
}

__device__ __forceinline__ uint64_t pack8(const float* f){
  int lo = 0, hi = 0;
  lo = __builtin_amdgcn_cvt_pk_fp8_f32(f[0], f[1], lo, false);
  lo = __builtin_amdgcn_cvt_pk_fp8_f32(f[2], f[3], lo, true);
  hi = __builtin_amdgcn_cvt_pk_fp8_f32(f[4], f[5], hi, false);
  hi = __builtin_amdgcn_cvt_pk_fp8_f32(f[6], f[7], hi, true);
  return (uint64_t)(uint32_t)lo | ((uint64_t)(uint32_t)hi << 32);
}

__global__ void initbar(unsigned* w){
  const int i = threadIdx.x;
  #pragma unroll
  for (int k = 0; k < 8; ++k) w[i + k*256] = 0u;   // zero first 8 KiB
}

// one-hop flag barrier over one bb-group of 64 blocks.
// flags[cb] = per-block sequence number (monotonic). Every block polls all 64.
__device__ __forceinline__ void gridbar(unsigned* flags, unsigned* abortf,
                                        unsigned seq, int cb, int* s_dead)
{
  __syncthreads();   // drains this block's stores (vmcnt(0)) before flagging
  if (*s_dead){ __syncthreads(); return; }
  const int tid = threadIdx.x;
  if (tid < 64){
    if (tid == 0) ast32(&flags[cb], seq);
    long long start = clock64();
    for (;;){
      unsigned f = (tid == cb) ? seq : ald32(&flags[tid]);
      if (__ballot(f >= seq) == ~0ull) break;
      if (ald32(abortf) != 0u){ if (tid == 0) *s_dead = 1; break; }
      if (clock64() - start > 40000000LL){
        if (tid == 0){ ast32(abortf, 1u); *s_dead = 1; }
        break;
      }
      __builtin_amdgcn_s_sleep(1);
    }
  }
  __syncthreads();
}

// 16(row-strip)x32 output tile, K=2048. A fp8 chunk-major in ws, NORMAL
// cacheable loads (coalesced 512B/chunk wave loads, all 64 issued upfront);
// B fp8 LDS fragment order.
__device__ __forceinline__ void run_gemm(const uint8_t* Ap, const uint8_t* Bp,
                                         f32x4& c0, f32x4& c1)
{
  uint64_t a[64];
  #pragma unroll
  for (int c = 0; c < 64; ++c)
    a[c] = *reinterpret_cast<const uint64_t*>(Ap + c*512);
  f32x4 e0 = {0.f,0.f,0.f,0.f};
  f32x4 e1 = e0, o0 = e0, o1 = e0;
  #pragma unroll
  for (int c = 0; c < 64; c += 2){
    long b00 = *reinterpret_cast<const long*>(Bp + c*1024);
    long b01 = *reinterpret_cast<const long*>(Bp + c*1024 + 512);
    long b10 = *reinterpret_cast<const long*>(Bp + c*1024 + 1024);
    long b11 = *reinterpret_cast<const long*>(Bp + c*1024 + 1536);
    e0 = __builtin_amdgcn_mfma_f32_16x16x32_fp8_fp8((long)a[c],   b00, e0, 0, 0, 0);
    e1 = __builtin_amdgcn_mfma_f32_16x16x32_fp8_fp8((long)a[c],   b01, e1, 0, 0, 0);
    o0 = __builtin_amdgcn_mfma_f32_16x16x32_fp8_fp8((long)a[c+1], b10, o0, 0, 0, 0);
    o1 = __builtin_amdgcn_mfma_f32_16x16x32_fp8_fp8((long)a[c+1], b11, o1, 0, 0, 0);
  }
  c0 = e0 + o0;
  c1 = e1 + o1;
}

extern "C" __global__ void __launch_bounds__(NTHR, 1)
rnn_main(const float* __restrict__ x, const float* __restrict__ ist,
         const float* __restrict__ W1, const float* __restrict__ b1,
         const float* __restrict__ W2, const float* __restrict__ b2,
         float* __restrict__ out, uint8_t* ws)
{
  __shared__ uint8_t Wlds[131072];   // W1 tile @0, W2 tile @65536 (fp8, fragment order)
  __shared__ float   xferf[64*34];   // transpose buffer (bytes in ph1, f32 in ph2)
  __shared__ int     s_dead;

  uint8_t* xfer8 = reinterpret_cast<uint8_t*>(xferf);

  float*   S32[2] = { reinterpret_cast<float*>(ws + WS_S32A),
                      reinterpret_cast<float*>(ws + WS_S32B) };
  uint8_t* S8[2]  = { ws + WS_S8A, ws + WS_S8B };
  uint8_t* H8     = ws + WS_H8;

  const int tid   = threadIdx.x;
  const int blk   = blockIdx.x;
  const int cb    = blk & 63;        // col block  -> cols cb*32..+32
  const int bb    = blk >> 6;        // batch group -> rows bb*64..+64
  const int lane  = tid & 63;
  const int wv    = tid >> 6;
  const int l15   = lane & 15;
  const int j0    = cb * 32;
  const int bbase = bb * 64;

  unsigned* flags  = reinterpret_cast<unsigned*>(ws + (size_t)bb*1024);
  unsigned* abortf = reinterpret_cast<unsigned*>(ws + 4096);

  if (tid == 0) s_dead = 0;

  // ---------- prologue: weight tiles -> LDS fp8 in exact MFMA fragment order
  {
    const int jh  = tid >> 4;        // 0..15
    const int kc0 = (tid & 15) * 8;  // 0..120
    for (int half = 0; half < 2; ++half){
      const int jc = jh + half*16;   // 0..31 local col
      const float* r1 = W1 + (size_t)(j0 + jc)*SW;
      const float* r2 = W2 + (size_t)(j0 + jc)*SW;
      #pragma unroll
      for (int p = 0; p < 16; ++p){
        const int k = kc0 + p*128;
        const int dst = (k >> 5)*1024 + (jc >> 4)*512
                      + (((jc & 15) + (((k >> 3) & 3) << 4)) << 3);
        float4 a  = *reinterpret_cast<const float4*>(r1 + k);
        float4 bq = *reinterpret_cast<const float4*>(r1 + k + 4);
        store_fp8x8(&Wlds[dst], a, bq);
        a  = *reinterpret_cast<const float4*>(r2 + k);
        bq = *reinterpret_cast<const float4*>(r2 + k + 4);
        store_fp8x8(&Wlds[65536 + dst], a, bq);
      }
    }
  }

  const float b1v0 = b1[j0 + l15];
  const float b1v1 = b1[j0 + 16 + l15];
  const float b2v0 = b2[j0 + l15];
  const float b2v1 = b2[j0 + 16 + l15];
  const float LIN = 0.99999f;
  const float UM  = (float)(1.0 - 0.99999);

  // ---------- init s(t=0): cols [0,256)=x[0], cols [256,2048)=UM*initial_state
  {
    const int r   = tid >> 2, g = tid & 3;
    const int row = bbase + r;
    const int col = j0 + g*8;
    float vv[8];
    if (col < INW){
      const float* src = x + (size_t)row*INW + col;
      *reinterpret_cast<float4*>(&vv[0]) = *reinterpret_cast<const float4*>(src);
      *reinterpret_cast<float4*>(&vv[4]) = *reinterpret_cast<const float4*>(src + 4);
    } else {
      #pragma unroll
      for (int k = 0; k < 8; ++k) vv[k] = UM * ist[col - INW + k];
    }
    float* d32 = S32[0] + (size_t)row*SW + col;
    const uint64_t* qq = reinterpret_cast<const uint64_t*>(vv);
    ast64(d32 + 0, qq[0]); ast64(d32 + 2, qq[1]);
    ast64(d32 + 4, qq[2]); ast64(d32 + 6, qq[3]);
    ast64(S8[0] + CHUNK_OFF(bb, r>>4, cb) + ((r & 15) + (g << 4))*8, pack8(vv));
  }

  unsigned seq = 0;
  gridbar(flags, abortf, ++seq, cb, &s_dead);

  const uint8_t* Bp1 = Wlds + lane*8;
  const uint8_t* Bp2 = Wlds + 65536 + lane*8;
  const size_t  abase = CHUNK_OFF(bb, wv, 0) + lane*8;

  for (int t = 0; t < SEQ; ++t){
    const uint8_t* S8c = S8[t & 1];
    uint8_t*       S8n = S8[(t + 1) & 1];
    const float*  S32c = S32[t & 1];
    float*        S32n = S32[(t + 1) & 1];

    const bool dog = (cb < 56) || (t == SEQ - 1);

    // ===== phase 1: H = relu(S @ W1^T + b1), all 2048 cols
    {
      f32x4 c0, c1;
      run_gemm(S8c + abase, Bp1, c0, c1);
      #pragma unroll
      for (int i = 0; i < 4; ++i){
        const int r = wv*16 + ((lane >> 4) << 2) + i;
        xfer8[r*32 + l15]      = f2fp8(fmaxf(c0[i] + b1v0, 0.f));
        xfer8[r*32 + 16 + l15] = f2fp8(fmaxf(c1[i] + b1v1, 0.f));
      }
      __syncthreads();
      {
        const int r = tid >> 2, g = tid & 3;
        uint64_t v = *reinterpret_cast<const uint64_t*>(&xfer8[r*32 + g*8]);
        ast64(H8 + CHUNK_OFF(bb, r>>4, cb) + ((r & 15) + (g << 4))*8, v);
      }
    }

    // prefetch phase-2's LIN*s operands (valid since end of step t-1; fresh in
    // cache-coherence terms because the last stale copy was inv'd at mid(t-2))
    float sv0[4], sv1[4];
    if (dog){
      #pragma unroll
      for (int i = 0; i < 4; ++i){
        const int r = wv*16 + ((lane >> 4) << 2) + i;
        const float* srow = S32c + (size_t)(bbase + r)*SW;
        sv0[i] = srow[j0 + l15];
        sv1[i] = srow[j0 + 16 + l15];
      }
    }

    gridbar(flags, abortf, ++seq, cb, &s_dead);
    // one L1/L2 invalidate per step: makes all sc1-written data (H8 this step,
    // S8/S32 rewrites for following steps) safe to read with cacheable loads.
    __builtin_amdgcn_fence(__ATOMIC_ACQUIRE, "agent");

    // ===== phase 2: carry = LIN*s + UM*(H @ W2^T + b2)
    if (dog){
      f32x4 c0, c1;
      run_gemm(H8 + abase, Bp2, c0, c1);
      if (t < SEQ - 1){
        #pragma unroll
        for (int i = 0; i < 4; ++i){
          const int r = wv*16 + ((lane >> 4) << 2) + i;
          xferf[r*34 + l15]      = LIN*sv0[i] + UM*(c0[i] + b2v0);
          xferf[r*34 + 16 + l15] = LIN*sv1[i] + UM*(c1[i] + b2v1);
        }
        __syncthreads();
        {
          const int r = tid >> 2, g = tid & 3;
          const float* src = &xferf[r*34 + g*8];
          uint64_t q0 = *reinterpret_cast<const uint64_t*>(src + 0);
          uint64_t q1 = *reinterpret_cast<const uint64_t*>(src + 2);
          uint64_t q2 = *reinterpret_cast<const uint64_t*>(src + 4);
          uint64_t q3 = *reinterpret_cast<const uint64_t*>(src + 6);
          float* d32 = S32n + (size_t)(bbase + r)*SW + j0 + 256 + g*8;
          ast64(d32 + 0, q0); ast64(d32 + 2, q1);
          ast64(d32 + 4, q2); ast64(d32 + 6, q3);
          ast64(S8n + CHUNK_OFF(bb, r>>4, cb + 8) + ((r & 15) + (g << 4))*8, pack8(src));
        }
      } else {
        // final step: outputs = carry[:,1792:2048], states = carry[:,0:1792]
        #pragma unroll
        for (int i = 0; i < 4; ++i){
          const int r   = wv*16 + ((lane >> 4) << 2) + i;
          const int row = bbase + r;
          const int col0 = j0 + l15;
          const int col1 = j0 + 16 + l15;
          float cr0 = LIN*sv0[i] + UM*(c0[i] + b2v0);
          float cr1 = LIN*sv1[i] + UM*(c1[i] + b2v1);
          if (col0 < STW) out[NB*INW + (size_t)row*STW + col0] = cr0;
          else            out[(size_t)row*INW + (col0 - STW)]  = cr0;
          if (col1 < STW) out[NB*INW + (size_t)row*STW + col1] = cr1;
          else            out[(size_t)row*INW + (col1 - STW)]  = cr1;
        }
      }
    } else {
      // x-copy: next s cols [0,256) = x[t+1]
      const int r   = tid >> 2, g = tid & 3;
      const int row = bbase + r;
      const int col = (cb - 56)*32 + g*8;
      const float* src = x + ((size_t)(t + 1)*NB + row)*INW + col;
      float vv[8];
      *reinterpret_cast<float4*>(&vv[0]) = *reinterpret_cast<const float4*>(src);
      *reinterpret_cast<float4*>(&vv[4]) = *reinterpret_cast<const float4*>(src + 4);
      float* d32 = S32n + (size_t)row*SW + col;
      const uint64_t* qq = reinterpret_cast<const uint64_t*>(vv);
      ast64(d32 + 0, qq[0]); ast64(d32 + 2, qq[1]);
      ast64(d32 + 4, qq[2]); ast64(d32 + 6, qq[3]);
      ast64(S8n + CHUNK_OFF(bb, r>>4, cb - 56) + ((r & 15) + (g << 4))*8, pack8(vv));
    }
    if (t < SEQ - 1)
      gridbar(flags, abortf, ++seq, cb, &s_dead);
  }
}

extern "C" void kernel_launch(void* const* d_in, const int* in_sizes, int n_in,
                              void* d_out, int out_size, void* d_ws, size_t ws_size,
                              hipStream_t stream)
{
  const float* x   = (const float*)d_in[0];
  const float* ist = (const float*)d_in[1];
  const float* W1  = (const float*)d_in[2];
  const float* b1  = (const float*)d_in[3];
  const float* W2  = (const float*)d_in[4];
  const float* b2  = (const float*)d_in[5];
  float* out  = (float*)d_out;
  uint8_t* ws = (uint8_t*)d_ws;

  hipLaunchKernelGGL(initbar, dim3(1), dim3(256), 0, stream, (unsigned*)ws);

  void* args[] = { (void*)&x, (void*)&ist, (void*)&W1, (void*)&b1,
                   (void*)&W2, (void*)&b2, (void*)&out, (void*)&ws };
  hipError_t e = hipLaunchCooperativeKernel((void*)rnn_main, dim3(NBLK), dim3(NTHR),
                                            args, 0, stream);
  if (e != hipSuccess){
    hipLaunchKernelGGL(rnn_main, dim3(NBLK), dim3(NTHR), 0, stream,
                       x, ist, W1, b1, W2, b2, out, ws);
  }
}

// Round 6
// 7942.786 us; speedup vs baseline: 1.5333x; 1.5333x over previous
//
#include <hip/hip_runtime.h>
#include <stdint.h>

#define SEQ   512
#define NB    256      // batch
#define SW    2048     // stream width
#define STW   1792     // state width
#define INW   256      // input width
#define NBLK  256
#define NTHR  512      // 8 waves: waves 0-3 K-lo, waves 4-7 K-hi

typedef float f32x4 __attribute__((ext_vector_type(4)));

// workspace layout (bytes)
// [0,4096): 4 group flag arrays, 1024B apart: flags[cb] per block
// [4096]: global abort flag
#define WS_S32A  8192
#define WS_S32B  (WS_S32A + NB*SW*4)
#define WS_S8A   (WS_S32B + NB*SW*4)
#define WS_S8B   (WS_S8A + NB*SW)
#define WS_H8    (WS_S8B + NB*SW)

// S8'/H8' chunk-major layout: [(bb*4+strip)*64 + chunk]*512 + l*8
// element (l, j) = row (strip*16 + (l&15)), k = chunk*32 + (l>>4)*8 + j
#define CHUNK_OFF(bb,strip,ch) (((size_t)(((bb)*4+(strip))*64 + (ch)))*512)

// ---------- agent-scope (sc1) helpers: STORES write through to the coherence
// point and push-invalidate remote L2 copies (proven by R5: unfenced cacheable
// re-reads of sc1-rewritten data validate bit-exactly). Loads: flags only.
__device__ __forceinline__ unsigned ald32(const void* p){
  return __hip_atomic_load((const unsigned*)p, __ATOMIC_RELAXED, __HIP_MEMORY_SCOPE_AGENT);
}
__device__ __forceinline__ void ast64(void* p, uint64_t v){
  __hip_atomic_store((uint64_t*)p, v, __ATOMIC_RELAXED, __HIP_MEMORY_SCOPE_AGENT);
}
__device__ __forceinline__ void ast32(void* p, unsigned v){
  __hip_atomic_store((unsigned*)p, v, __ATOMIC_RELAXED, __HIP_MEMORY_SCOPE_AGENT);
}

__device__ __forceinline__ uint8_t f2fp8(float v){
  int p = __builtin_amdgcn_cvt_pk_fp8_f32(v, 0.0f, 0, false);
  return (uint8_t)(p & 0xFF);
}

__device__ __forceinline__ void store_fp8x8(uint8_t* dst, float4 a, float4 b){
  int lo = 0, hi = 0;
  lo = __builtin_amdgcn_cvt_pk_fp8_f32(a.x, a.y, lo, false);
  lo = __builtin_amdgcn_cvt_pk_fp8_f32(a.z, a.w, lo, true);
  hi = __builtin_amdgcn_cvt_pk_fp8_f32(b.x, b.y, hi, false);
  hi = __builtin_amdgcn_cvt_pk_fp8_f32(b.z, b.w, hi, true);
  int2 v; v.x = lo; v.y = hi;
  *reinterpret_cast<int2*>(dst) = v;
}

__device__ __forceinline__ uint64_t pack8(const float* f){
  int lo = 0, hi = 0;
  lo = __builtin_amdgcn_cvt_pk_fp8_f32(f[0], f[1], lo, false);
  lo = __builtin_amdgcn_cvt_pk_fp8_f32(f[2], f[3], lo, true);
  hi = __builtin_amdgcn_cvt_pk_fp8_f32(f[4], f[5], hi, false);
  hi = __builtin_amdgcn_cvt_pk_fp8_f32(f[6], f[7], hi, true);
  return (uint64_t)(uint32_t)lo | ((uint64_t)(uint32_t)hi << 32);
}

__global__ void initbar(unsigned* w){
  const int i = threadIdx.x;
  #pragma unroll
  for (int k = 0; k < 8; ++k) w[i + k*256] = 0u;   // zero first 8 KiB
}

// one-hop flag barrier over one bb-group of 64 blocks.
// flags[cb] = per-block sequence number (monotonic). Every block polls all 64.
__device__ __forceinline__ void gridbar(unsigned* flags, unsigned* abortf,
                                        unsigned seq, int cb, int* s_dead)
{
  __syncthreads();   // drains this block's stores (vmcnt(0)) before flagging
  if (*s_dead){ __syncthreads(); return; }
  const int tid = threadIdx.x;
  if (tid < 64){
    if (tid == 0) ast32(&flags[cb], seq);
    long long start = clock64();
    for (;;){
      unsigned f = (tid == cb) ? seq : ald32(&flags[tid]);
      if (__ballot(f >= seq) == ~0ull) break;
      if (ald32(abortf) != 0u){ if (tid == 0) *s_dead = 1; break; }
      if (clock64() - start > 40000000LL){
        if (tid == 0){ ast32(abortf, 1u); *s_dead = 1; }
        break;
      }
      __builtin_amdgcn_s_sleep(1);
    }
  }
  __syncthreads();
  asm volatile("" ::: "memory");   // no load hoisting above the barrier
}

// 16(row-strip)x32 output tile, K-half=1024 (32 chunks). A fp8 chunk-major,
// plain cacheable coalesced loads (512B/chunk wave loads, all issued upfront);
// B fp8 LDS fragment order. Partial sums -> c0,c1.
__device__ __forceinline__ void run_gemm(const uint8_t* Ap, const uint8_t* Bp,
                                         f32x4& c0, f32x4& c1)
{
  uint64_t a[32];
  #pragma unroll
  for (int c = 0; c < 32; ++c)
    a[c] = *reinterpret_cast<const uint64_t*>(Ap + c*512);
  f32x4 e0 = {0.f,0.f,0.f,0.f};
  f32x4 e1 = e0, o0 = e0, o1 = e0;
  #pragma unroll
  for (int c = 0; c < 32; c += 2){
    long b00 = *reinterpret_cast<const long*>(Bp + c*1024);
    long b01 = *reinterpret_cast<const long*>(Bp + c*1024 + 512);
    long b10 = *reinterpret_cast<const long*>(Bp + c*1024 + 1024);
    long b11 = *reinterpret_cast<const long*>(Bp + c*1024 + 1536);
    e0 = __builtin_amdgcn_mfma_f32_16x16x32_fp8_fp8((long)a[c],   b00, e0, 0, 0, 0);
    e1 = __builtin_amdgcn_mfma_f32_16x16x32_fp8_fp8((long)a[c],   b01, e1, 0, 0, 0);
    o0 = __builtin_amdgcn_mfma_f32_16x16x32_fp8_fp8((long)a[c+1], b10, o0, 0, 0, 0);
    o1 = __builtin_amdgcn_mfma_f32_16x16x32_fp8_fp8((long)a[c+1], b11, o1, 0, 0, 0);
  }
  c0 = e0 + o0;
  c1 = e1 + o1;
}

extern "C" __global__ void __launch_bounds__(NTHR, 2)
rnn_main(const float* __restrict__ x, const float* __restrict__ ist,
         const float* __restrict__ W1, const float* __restrict__ b1,
         const float* __restrict__ W2, const float* __restrict__ b2,
         float* __restrict__ out, uint8_t* ws)
{
  __shared__ uint8_t Wlds[131072];   // W1 tile @0, W2 tile @65536 (fp8, fragment order)
  __shared__ float   xferf[64*34];   // transpose buffer (bytes in ph1, f32 in ph2)
  __shared__ float   redf[4][8][64]; // K-split partial-sum exchange (8 KB)
  __shared__ int     s_dead;

  uint8_t* xfer8 = reinterpret_cast<uint8_t*>(xferf);

  float*   S32[2] = { reinterpret_cast<float*>(ws + WS_S32A),
                      reinterpret_cast<float*>(ws + WS_S32B) };
  uint8_t* S8[2]  = { ws + WS_S8A, ws + WS_S8B };
  uint8_t* H8     = ws + WS_H8;

  const int tid   = threadIdx.x;
  const int blk   = blockIdx.x;
  const int cb    = blk & 63;        // col block  -> cols cb*32..+32
  const int bb    = blk >> 6;        // batch group -> rows bb*64..+64
  const int lane  = tid & 63;
  const int wv    = tid >> 6;        // 0..7
  const int strip = wv & 3;          // 16-row strip
  const int half  = wv >> 2;         // K-half
  const int l15   = lane & 15;
  const int j0    = cb * 32;
  const int bbase = bb * 64;

  unsigned* flags  = reinterpret_cast<unsigned*>(ws + (size_t)bb*1024);
  unsigned* abortf = reinterpret_cast<unsigned*>(ws + 4096);

  if (tid == 0) s_dead = 0;

  // ---------- prologue (tid<256): weight tiles -> LDS fp8 in fragment order
  if (tid < 256){
    const int jh  = tid >> 4;        // 0..15
    const int kc0 = (tid & 15) * 8;  // 0..120
    for (int hf = 0; hf < 2; ++hf){
      const int jc = jh + hf*16;     // 0..31 local col
      const float* r1 = W1 + (size_t)(j0 + jc)*SW;
      const float* r2 = W2 + (size_t)(j0 + jc)*SW;
      #pragma unroll
      for (int p = 0; p < 16; ++p){
        const int k = kc0 + p*128;
        const int dst = (k >> 5)*1024 + (jc >> 4)*512
                      + (((jc & 15) + (((k >> 3) & 3) << 4)) << 3);
        float4 a  = *reinterpret_cast<const float4*>(r1 + k);
        float4 bq = *reinterpret_cast<const float4*>(r1 + k + 4);
        store_fp8x8(&Wlds[dst], a, bq);
        a  = *reinterpret_cast<const float4*>(r2 + k);
        bq = *reinterpret_cast<const float4*>(r2 + k + 4);
        store_fp8x8(&Wlds[65536 + dst], a, bq);
      }
    }
  }

  const float b1v0 = b1[j0 + l15];
  const float b1v1 = b1[j0 + 16 + l15];
  const float b2v0 = b2[j0 + l15];
  const float b2v1 = b2[j0 + 16 + l15];
  const float LIN = 0.99999f;
  const float UM  = (float)(1.0 - 0.99999);

  // ---------- init s(t=0): cols [0,256)=x[0], cols [256,2048)=UM*initial_state
  if (tid < 256){
    const int r   = tid >> 2, g = tid & 3;
    const int row = bbase + r;
    const int col = j0 + g*8;
    float vv[8];
    if (col < INW){
      const float* src = x + (size_t)row*INW + col;
      *reinterpret_cast<float4*>(&vv[0]) = *reinterpret_cast<const float4*>(src);
      *reinterpret_cast<float4*>(&vv[4]) = *reinterpret_cast<const float4*>(src + 4);
    } else {
      #pragma unroll
      for (int k = 0; k < 8; ++k) vv[k] = UM * ist[col - INW + k];
    }
    float* d32 = S32[0] + (size_t)row*SW + col;
    const uint64_t* qq = reinterpret_cast<const uint64_t*>(vv);
    ast64(d32 + 0, qq[0]); ast64(d32 + 2, qq[1]);
    ast64(d32 + 4, qq[2]); ast64(d32 + 6, qq[3]);
    ast64(S8[0] + CHUNK_OFF(bb, r>>4, cb) + ((r & 15) + (g << 4))*8, pack8(vv));
  }

  unsigned seq = 0;
  gridbar(flags, abortf, ++seq, cb, &s_dead);

  // per-wave operand bases (K-half offset folded in)
  const uint8_t* Bp1 = Wlds + (size_t)half*32768 + lane*8;
  const uint8_t* Bp2 = Wlds + 65536 + (size_t)half*32768 + lane*8;
  const size_t  abase = CHUNK_OFF(bb, strip, half*32) + lane*8;

  for (int t = 0; t < SEQ; ++t){
    const uint8_t* S8c = S8[t & 1];
    const float*  S32c = S32[t & 1];
    uint8_t*       S8n = S8[(t + 1) & 1];
    float*        S32n = S32[(t + 1) & 1];

    const bool dog = (cb < 56) || (t == SEQ - 1);

    // ===== phase 1: H = relu(S @ W1^T + b1), all 2048 cols
    {
      f32x4 c0, c1;
      run_gemm(S8c + abase, Bp1, c0, c1);
      if (half == 1){
        #pragma unroll
        for (int i = 0; i < 4; ++i){
          redf[strip][i][lane]     = c0[i];
          redf[strip][4 + i][lane] = c1[i];
        }
      }
      __syncthreads();
      if (half == 0){
        #pragma unroll
        for (int i = 0; i < 4; ++i){
          c0[i] += redf[strip][i][lane];
          c1[i] += redf[strip][4 + i][lane];
          const int r = strip*16 + ((lane >> 4) << 2) + i;
          xfer8[r*32 + l15]      = f2fp8(fmaxf(c0[i] + b1v0, 0.f));
          xfer8[r*32 + 16 + l15] = f2fp8(fmaxf(c1[i] + b1v1, 0.f));
        }
      }
      __syncthreads();
      if (tid < 256){
        const int r = tid >> 2, g = tid & 3;
        uint64_t v = *reinterpret_cast<const uint64_t*>(&xfer8[r*32 + g*8]);
        ast64(H8 + CHUNK_OFF(bb, r>>4, cb) + ((r & 15) + (g << 4))*8, v);
      }
    }

    // prefetch phase-2's LIN*s operands (valid since end of step t-1)
    float sv0[4], sv1[4];
    if (dog && half == 0){
      #pragma unroll
      for (int i = 0; i < 4; ++i){
        const int r = strip*16 + ((lane >> 4) << 2) + i;
        const float* srow = S32c + (size_t)(bbase + r)*SW;
        sv0[i] = srow[j0 + l15];
        sv1[i] = srow[j0 + 16 + l15];
      }
    }

    gridbar(flags, abortf, ++seq, cb, &s_dead);

    // ===== phase 2: carry = LIN*s + UM*(H @ W2^T + b2)
    if (dog){
      f32x4 c0, c1;
      run_gemm(H8 + abase, Bp2, c0, c1);
      if (half == 1){
        #pragma unroll
        for (int i = 0; i < 4; ++i){
          redf[strip][i][lane]     = c0[i];
          redf[strip][4 + i][lane] = c1[i];
        }
      }
      __syncthreads();
      if (t < SEQ - 1){
        if (half == 0){
          #pragma unroll
          for (int i = 0; i < 4; ++i){
            c0[i] += redf[strip][i][lane];
            c1[i] += redf[strip][4 + i][lane];
            const int r = strip*16 + ((lane >> 4) << 2) + i;
            xferf[r*34 + l15]      = LIN*sv0[i] + UM*(c0[i] + b2v0);
            xferf[r*34 + 16 + l15] = LIN*sv1[i] + UM*(c1[i] + b2v1);
          }
        }
        __syncthreads();
        if (tid < 256){
          const int r = tid >> 2, g = tid & 3;
          const float* src = &xferf[r*34 + g*8];
          uint64_t q0 = *reinterpret_cast<const uint64_t*>(src + 0);
          uint64_t q1 = *reinterpret_cast<const uint64_t*>(src + 2);
          uint64_t q2 = *reinterpret_cast<const uint64_t*>(src + 4);
          uint64_t q3 = *reinterpret_cast<const uint64_t*>(src + 6);
          float* d32 = S32n + (size_t)(bbase + r)*SW + j0 + 256 + g*8;
          ast64(d32 + 0, q0); ast64(d32 + 2, q1);
          ast64(d32 + 4, q2); ast64(d32 + 6, q3);
          ast64(S8n + CHUNK_OFF(bb, r>>4, cb + 8) + ((r & 15) + (g << 4))*8, pack8(src));
        }
      } else {
        // final step: outputs = carry[:,1792:2048], states = carry[:,0:1792]
        if (half == 0){
          #pragma unroll
          for (int i = 0; i < 4; ++i){
            c0[i] += redf[strip][i][lane];
            c1[i] += redf[strip][4 + i][lane];
            const int r   = strip*16 + ((lane >> 4) << 2) + i;
            const int row = bbase + r;
            const int col0 = j0 + l15;
            const int col1 = j0 + 16 + l15;
            float cr0 = LIN*sv0[i] + UM*(c0[i] + b2v0);
            float cr1 = LIN*sv1[i] + UM*(c1[i] + b2v1);
            if (col0 < STW) out[NB*INW + (size_t)row*STW + col0] = cr0;
            else            out[(size_t)row*INW + (col0 - STW)]  = cr0;
            if (col1 < STW) out[NB*INW + (size_t)row*STW + col1] = cr1;
            else            out[(size_t)row*INW + (col1 - STW)]  = cr1;
          }
        }
      }
    } else {
      // x-copy: next s cols [0,256) = x[t+1]
      if (tid < 256){
        const int r   = tid >> 2, g = tid & 3;
        const int row = bbase + r;
        const int col = (cb - 56)*32 + g*8;
        const float* src = x + ((size_t)(t + 1)*NB + row)*INW + col;
        float vv[8];
        *reinterpret_cast<float4*>(&vv[0]) = *reinterpret_cast<const float4*>(src);
        *reinterpret_cast<float4*>(&vv[4]) = *reinterpret_cast<const float4*>(src + 4);
        float* d32 = S32n + (size_t)row*SW + col;
        const uint64_t* qq = reinterpret_cast<const uint64_t*>(vv);
        ast64(d32 + 0, qq[0]); ast64(d32 + 2, qq[1]);
        ast64(d32 + 4, qq[2]); ast64(d32 + 6, qq[3]);
        ast64(S8n + CHUNK_OFF(bb, r>>4, cb - 56) + ((r & 15) + (g << 4))*8, pack8(vv));
      }
    }
    if (t < SEQ - 1)
      gridbar(flags, abortf, ++seq, cb, &s_dead);
  }
}

extern "C" void kernel_launch(void* const* d_in, const int* in_sizes, int n_in,
                              void* d_out, int out_size, void* d_ws, size_t ws_size,
                              hipStream_t stream)
{
  const float* x   = (const float*)d_in[0];
  const float* ist = (const float*)d_in[1];
  const float* W1  = (const float*)d_in[2];
  const float* b1  = (const float*)d_in[3];
  const float* W2  = (const float*)d_in[4];
  const float* b2  = (const float*)d_in[5];
  float* out  = (float*)d_out;
  uint8_t* ws = (uint8_t*)d_ws;

  hipLaunchKernelGGL(initbar, dim3(1), dim3(256), 0, stream, (unsigned*)ws);

  void* args[] = { (void*)&x, (void*)&ist, (void*)&W1, (void*)&b1,
                   (void*)&W2, (void*)&b2, (void*)&out, (void*)&ws };
  hipError_t e = hipLaunchCooperativeKernel((void*)rnn_main, dim3(NBLK), dim3(NTHR),
                                            args, 0, stream);
  if (e != hipSuccess){
    hipLaunchKernelGGL(rnn_main, dim3(NBLK), dim3(NTHR), 0, stream,
                       x, ist, W1, b1, W2, b2, out, ws);
  }
}